// Round 3
// baseline (220.959 us; speedup 1.0000x reference)
//
#include <hip/hip_runtime.h>
#include <math.h>

#pragma clang fp contract(off)

#define BB   8
#define NGT  60
#define LL   21504
#define CC   15
#define KTOP 13
#define BGI  15
#define EPSF 1e-9f
#define SSEG 8
#define SEGLEN (LL / SSEG)   // 2688

// AABB of rotated box, replicating reference _box_min_max op order.
__device__ __forceinline__ float4 rbox_aabb(float cx, float cy, float w, float h, float r) {
    float cr = (float)cos((double)r);
    float sr = (float)sin((double)r);
    float dx = (w * 0.5f) * cr;
    float dy = (h * 0.5f) * sr;
    float xs[4] = {cx - dx, cx + dx, cx + dx, cx - dx};
    float ys[4] = {cy - dy, cy - dy, cy + dy, cy + dy};
    float mnx = 1e30f, mxx = -1e30f, mny = 1e30f, mxy = -1e30f;
#pragma unroll
    for (int k = 0; k < 4; ++k) {
        float tx = xs[k] - cx, ty = ys[k] - cy;
        float xr = (cx + tx * cr) - ty * sr;
        float yr = (cy + tx * sr) + ty * cr;
        mnx = fminf(mnx, xr); mxx = fmaxf(mxx, xr);
        mny = fminf(mny, yr); mxy = fmaxf(mxy, yr);
    }
    return make_float4(mnx, mxx, mny, mxy);
}

__device__ __forceinline__ float iou_pair(float4 g, float a1, float4 p, float a2) {
    float iw = fmaxf(fminf(g.y, p.y) - fmaxf(g.x, p.x), 0.0f);
    float ih = fmaxf(fminf(g.w, p.w) - fmaxf(g.z, p.z), 0.0f);
    float inter = iw * ih;
    float denom = ((a1 + a2) - inter) + EPSF;
    float q = inter / denom;
    return fminf(fmaxf(q, 0.0f), 1.0f);
}

// ---------- fused prep: pred boxes, score transpose, gt boxes, zero-init ----------
__global__ void prep_kernel(const float* __restrict__ pr,
                            const float* __restrict__ ps,
                            const float* __restrict__ gt,
                            const float* __restrict__ pad,
                            float4* __restrict__ pbox,
                            float* __restrict__ parea,
                            float* __restrict__ psT,
                            float4* __restrict__ gbox,
                            float4* __restrict__ gtrig,
                            float4* __restrict__ ggeom,
                            int* __restrict__ cnt,
                            int* __restrict__ claim,
                            unsigned* __restrict__ maxM,
                            unsigned* __restrict__ maxI) {
    int i = blockIdx.x * blockDim.x + threadIdx.x;  // b*LL + j
    if (i >= BB * LL) return;
    if (i < BB * NGT) {                 // gt prep + per-gt zero-init
        float cx = gt[i * 5 + 0], cy = gt[i * 5 + 1];
        float w  = gt[i * 5 + 2], h  = gt[i * 5 + 3], r = gt[i * 5 + 4];
        gbox[i] = rbox_aabb(cx, cy, w, h, r);
        float cr = (float)cos((double)r);
        float sr = (float)sin((double)r);
        gtrig[i] = make_float4(cr, sr, w * h, pad[i]);
        ggeom[i] = make_float4(cx, cy, w * 0.5f, h * 0.5f);
        maxM[i] = 0u; maxI[i] = 0u;
    }
    cnt[i] = 0; claim[i] = 0;
    float cx = pr[i * 5 + 0], cy = pr[i * 5 + 1];
    float w  = pr[i * 5 + 2], h  = pr[i * 5 + 3], r = pr[i * 5 + 4];
    pbox[i] = rbox_aabb(cx, cy, w, h, r);
    parea[i] = w * h;
    int b = i / LL, j = i % LL;
#pragma unroll
    for (int c = 0; c < CC; ++c)
        psT[((size_t)b * CC + c) * LL + j] = ps[(size_t)i * CC + c];  // coalesced write
}

// ---------- topk phase 1: per-(row,segment) top-13 (1 wave per block) ----------
// Each thread scans SEGLEN/64=42 elements (ascending j) into a sorted
// (value desc, index asc) register top-13; wave-shuffle merge pops the
// segment's top-13. Stability matches jax.lax.top_k exactly.
__global__ __launch_bounds__(64) void topk_part1(
        const float* __restrict__ psT,
        const int* __restrict__ labels,
        const float* __restrict__ anch,
        const float4* __restrict__ pbox,
        const float* __restrict__ parea,
        const float4* __restrict__ gbox,
        const float4* __restrict__ gtrig,
        const float4* __restrict__ ggeom,
        float* __restrict__ candV,
        int* __restrict__ candJ) {
    int bi = blockIdx.y;            // b*NGT + i
    int s  = blockIdx.x;            // segment
    float4 tg = gtrig[bi];
    if (tg.w == 0.0f) return;       // padded gt (uniform per block)
    int b = bi / NGT;
    float4 g  = gbox[bi];
    float4 gg = ggeom[bi];
    float  a1 = tg.z;
    const float*  srow = psT + ((size_t)b * CC + labels[bi]) * LL;
    const float4* pb   = pbox + (size_t)b * LL;
    const float*  pa   = parea + (size_t)b * LL;
    const float2* an2  = (const float2*)anch;
    int t = threadIdx.x;

    float lv[KTOP]; int li[KTOP];
#pragma unroll
    for (int k = 0; k < KTOP; ++k) { lv[k] = -1.0f; li[k] = 0x7fffffff; }

    int base = s * SEGLEN;
    for (int e = t; e < SEGLEN; e += 64) {
        int j = base + e;
        float4 p = pb[j];
        float a2 = pa[j];
        float iou = iou_pair(g, a1, p, a2);
        float2 ap = an2[j];
        float dx = ap.x - gg.x, dy = ap.y - gg.y;
        float xl = dx * tg.x + dy * tg.y;
        float yl = dy * tg.x - dx * tg.y;
        bool ing = (fabsf(xl) <= gg.z) && (fabsf(yl) <= gg.w);
        float i2 = iou * iou;
        float v = ing ? (srow[j] * (i2 * i2 * i2)) : 0.0f;
        if (v > lv[KTOP - 1]) {     // per-thread j ascending -> stable
            lv[KTOP - 1] = v; li[KTOP - 1] = j;
#pragma unroll
            for (int k = KTOP - 1; k > 0; --k) {
                bool sw = lv[k] > lv[k - 1];
                float tv = sw ? lv[k - 1] : lv[k];
                int   ti = sw ? li[k - 1] : li[k];
                lv[k - 1] = sw ? lv[k] : lv[k - 1];
                li[k - 1] = sw ? li[k] : li[k - 1];
                lv[k] = tv; li[k] = ti;
            }
        }
    }

    // wave merge: 13 rounds of butterfly argmax over the 64 list heads
    size_t outIdx = ((size_t)bi * SSEG + s) * KTOP;
    for (int r = 0; r < KTOP; ++r) {
        float ov = lv[0]; int oj = li[0];
#pragma unroll
        for (int off = 32; off > 0; off >>= 1) {
            float v2 = __shfl_xor(ov, off, 64);
            int   j2 = __shfl_xor(oj, off, 64);
            if (v2 > ov || (v2 == ov && j2 < oj)) { ov = v2; oj = j2; }
        }
        // all lanes now agree on (ov, oj)
        if (t == 0) { candV[outIdx + r] = ov; candJ[outIdx + r] = oj; }
        if (li[0] == oj) {          // j unique -> exactly one lane pops
#pragma unroll
            for (int k = 0; k < KTOP - 1; ++k) { lv[k] = lv[k + 1]; li[k] = li[k + 1]; }
            lv[KTOP - 1] = -1.0f; li[KTOP - 1] = 0x7fffffff;
        }
    }
}

// ---------- topk phase 2: merge 8x13 candidates per row -> atomics ----------
__global__ __launch_bounds__(128) void topk_part2(
        const float4* __restrict__ gtrig,
        const float4* __restrict__ ggeom,
        const float* __restrict__ anch,
        const float* __restrict__ candV,
        const int* __restrict__ candJ,
        int* __restrict__ cnt,
        int* __restrict__ claim) {
    int bi = blockIdx.x;
    float4 tg = gtrig[bi];
    if (tg.w == 0.0f) return;
    int b = bi / NGT, i = bi % NGT;
    float4 gg = ggeom[bi];
    int t = threadIdx.x;
    float v = -2.0f; int j = 0x7fffffff;
    if (t < SSEG * KTOP) {
        v = candV[(size_t)bi * SSEG * KTOP + t];
        j = candJ[(size_t)bi * SSEG * KTOP + t];
    }
    __shared__ float sv[2]; __shared__ int si[2];
    for (int r = 0; r < KTOP; ++r) {
        float ov = v; int oj = j;
#pragma unroll
        for (int off = 32; off > 0; off >>= 1) {
            float v2 = __shfl_xor(ov, off, 64);
            int   j2 = __shfl_xor(oj, off, 64);
            if (v2 > ov || (v2 == ov && j2 < oj)) { ov = v2; oj = j2; }
        }
        if ((t & 63) == 0) { sv[t >> 6] = ov; si[t >> 6] = oj; }
        __syncthreads();
        float bv = sv[0]; int bj = si[0];
        if (sv[1] > bv || (sv[1] == bv && si[1] < bj)) { bv = sv[1]; bj = si[1]; }
        if (t == 0) {
            bool in = (bv > 0.0f);   // positive metric implies in_gts
            if (!in) {               // zero-metric pick: explicit in_gts test
                float2 ap = ((const float2*)anch)[bj];
                float dx = ap.x - gg.x, dy = ap.y - gg.y;
                float xl = dx * tg.x + dy * tg.y;
                float yl = dy * tg.x - dx * tg.y;
                in = (fabsf(xl) <= gg.z) && (fabsf(yl) <= gg.w);
            }
            if (in) {
                atomicAdd(&cnt[b * LL + bj], 1);
                atomicMax(&claim[b * LL + bj], i);
            }
        }
        if (j == bj) v = -2.0f;      // consume winner (j unique per row)
        __syncthreads();
    }
}

// ---------- resolve: assign one gt (or none) per anchor; per-gt maxes ----------
__global__ void resolve_kernel(const float* __restrict__ psT,
                               const int* __restrict__ labels,
                               const float4* __restrict__ pbox,
                               const float* __restrict__ parea,
                               const float4* __restrict__ gbox,
                               const float4* __restrict__ gtrig,
                               const int* __restrict__ cnt,
                               const int* __restrict__ claim,
                               int* __restrict__ assigned,
                               float* __restrict__ aMetric,
                               unsigned* __restrict__ maxM,
                               unsigned* __restrict__ maxI) {
    __shared__ float4 sB[NGT];
    __shared__ float  sA[NGT];
    int b = blockIdx.y, t = threadIdx.x;
    if (t < NGT) { sB[t] = gbox[b * NGT + t]; sA[t] = gtrig[b * NGT + t].z; }
    __syncthreads();
    int j = blockIdx.x * blockDim.x + t;
    if (j >= LL) return;
    int p = b * LL + j;
    int c = cnt[p];
    if (c == 0) { assigned[p] = -1; aMetric[p] = 0.0f; return; }
    float4 pb = pbox[p];
    float a2 = parea[p];
    int a; float iouv;
    if (c == 1) {
        a = claim[p];
        iouv = iou_pair(sB[a], sA[a], pb, a2);
    } else {
        float best = -1.0f; int bi = 0;
        for (int i = 0; i < NGT; ++i) {
            float v = iou_pair(sB[i], sA[i], pb, a2);
            if (v > best) { best = v; bi = i; }       // ties -> lowest index
        }
        a = bi; iouv = best;
    }
    float sc = psT[((size_t)b * CC + labels[b * NGT + a]) * LL + j];
    float i2 = iouv * iouv;
    float m = sc * (i2 * i2 * i2);
    assigned[p] = a;
    aMetric[p] = m;
    atomicMax(&maxM[b * NGT + a], __float_as_uint(m));
    atomicMax(&maxI[b * NGT + a], __float_as_uint(iouv));
}

// ---------- finalize: write all 5 outputs (float32, concatenated) ----------
__global__ void finalize_kernel(const float* __restrict__ gt,
                                const int* __restrict__ labels,
                                const int* __restrict__ crowd,
                                const int* __restrict__ assigned,
                                const float* __restrict__ aMetric,
                                const unsigned* __restrict__ maxM,
                                const unsigned* __restrict__ maxI,
                                float* __restrict__ out) {
    int b = blockIdx.y;
    int j = blockIdx.x * blockDim.x + threadIdx.x;
    if (j >= LL) return;
    int p = b * LL + j;
    int a = assigned[p];
    bool pos = (a >= 0);
    int idx = pos ? a : 0;
    int lab = labels[b * NGT + idx];
    int cw  = crowd[b * NGT + idx];
    const size_t O0 = 0;
    const size_t O1 = (size_t)BB * LL;
    const size_t O2 = O1 + (size_t)BB * LL * 5;
    const size_t O3 = O2 + (size_t)BB * LL * CC;
    const size_t O4 = O3 + (size_t)BB * LL;
    out[O0 + p] = pos ? (float)lab : (float)BGI;
    const float* gb = gt + (size_t)(b * NGT + idx) * 5;
#pragma unroll
    for (int k = 0; k < 5; ++k) out[O1 + (size_t)p * 5 + k] = gb[k];
    float per = 0.0f;
    if (pos) {
        float mm = __uint_as_float(maxM[b * NGT + a]);
        float mi = __uint_as_float(maxI[b * NGT + a]);
        per = aMetric[p] / (mm + EPSF) * mi;
    }
#pragma unroll
    for (int c = 0; c < CC; ++c) {
        float s = (pos && cw == 0 && c == lab) ? per : 0.0f;
        out[O2 + (size_t)p * CC + c] = s;
    }
    out[O3 + p] = (float)idx;
    out[O4 + p] = (float)cw;
}

extern "C" void kernel_launch(void* const* d_in, const int* in_sizes, int n_in,
                              void* d_out, int out_size, void* d_ws, size_t ws_size,
                              hipStream_t stream) {
    const float* pred_scores = (const float*)d_in[0];
    const float* pred_rboxes = (const float*)d_in[1];
    const float* anchor_pts  = (const float*)d_in[2];
    const int*   gt_labels   = (const int*)d_in[3];
    const float* gt_bboxes   = (const float*)d_in[4];
    // d_in[5] = gt_poses (unused)
    const int*   gt_crowd    = (const int*)d_in[6];
    const float* pad_gt      = (const float*)d_in[7];
    float* out = (float*)d_out;

    char* ws = (char*)d_ws;
    size_t off = 0;
    auto alloc = [&](size_t bytes) {
        void* pp = ws + off;
        off += (bytes + 255) & ~(size_t)255;
        return pp;
    };
    float*  psT   = (float*)alloc((size_t)BB * CC * LL * 4);
    float4* pbox  = (float4*)alloc((size_t)BB * LL * 16);
    float*  parea = (float*)alloc((size_t)BB * LL * 4);
    float4* gbox  = (float4*)alloc((size_t)BB * NGT * 16);
    float4* gtrig = (float4*)alloc((size_t)BB * NGT * 16);
    float4* ggeom = (float4*)alloc((size_t)BB * NGT * 16);
    int* cnt        = (int*)alloc((size_t)BB * LL * 4);
    int* claim      = (int*)alloc((size_t)BB * LL * 4);
    unsigned* maxM  = (unsigned*)alloc((size_t)BB * NGT * 4);
    unsigned* maxI  = (unsigned*)alloc((size_t)BB * NGT * 4);
    int*   assigned = (int*)alloc((size_t)BB * LL * 4);
    float* aMetric  = (float*)alloc((size_t)BB * LL * 4);
    float* candV    = (float*)alloc((size_t)BB * NGT * SSEG * KTOP * 4);
    int*   candJ    = (int*)alloc((size_t)BB * NGT * SSEG * KTOP * 4);

    prep_kernel<<<dim3((BB * LL + 255) / 256), dim3(256), 0, stream>>>(
        pred_rboxes, pred_scores, gt_bboxes, pad_gt,
        pbox, parea, psT, gbox, gtrig, ggeom, cnt, claim, maxM, maxI);
    topk_part1<<<dim3(SSEG, BB * NGT), dim3(64), 0, stream>>>(
        psT, gt_labels, anchor_pts, pbox, parea, gbox, gtrig, ggeom, candV, candJ);
    topk_part2<<<dim3(BB * NGT), dim3(128), 0, stream>>>(
        gtrig, ggeom, anchor_pts, candV, candJ, cnt, claim);
    resolve_kernel<<<dim3(LL / 256, BB), dim3(256), 0, stream>>>(
        psT, gt_labels, pbox, parea, gbox, gtrig, cnt, claim,
        assigned, aMetric, maxM, maxI);
    finalize_kernel<<<dim3(LL / 256, BB), dim3(256), 0, stream>>>(
        gt_bboxes, gt_labels, gt_crowd, assigned, aMetric, maxM, maxI, out);
}

// Round 4
// 217.890 us; speedup vs baseline: 1.0141x; 1.0141x over previous
//
#include <hip/hip_runtime.h>
#include <math.h>

#pragma clang fp contract(off)

#define BB   8
#define NGT  60
#define LL   21504
#define CC   15
#define KTOP 13
#define BGI  15
#define EPSF 1e-9f
#define SSEG 8
#define SEGLEN (LL / SSEG)   // 2688

// AABB of rotated box, replicating reference _box_min_max op order.
__device__ __forceinline__ float4 rbox_aabb(float cx, float cy, float w, float h, float r) {
    float cr = (float)cos((double)r);
    float sr = (float)sin((double)r);
    float dx = (w * 0.5f) * cr;
    float dy = (h * 0.5f) * sr;
    float xs[4] = {cx - dx, cx + dx, cx + dx, cx - dx};
    float ys[4] = {cy - dy, cy - dy, cy + dy, cy + dy};
    float mnx = 1e30f, mxx = -1e30f, mny = 1e30f, mxy = -1e30f;
#pragma unroll
    for (int k = 0; k < 4; ++k) {
        float tx = xs[k] - cx, ty = ys[k] - cy;
        float xr = (cx + tx * cr) - ty * sr;
        float yr = (cy + tx * sr) + ty * cr;
        mnx = fminf(mnx, xr); mxx = fmaxf(mxx, xr);
        mny = fminf(mny, yr); mxy = fmaxf(mxy, yr);
    }
    return make_float4(mnx, mxx, mny, mxy);
}

__device__ __forceinline__ float iou_pair(float4 g, float a1, float4 p, float a2) {
    float iw = fmaxf(fminf(g.y, p.y) - fmaxf(g.x, p.x), 0.0f);
    float ih = fmaxf(fminf(g.w, p.w) - fmaxf(g.z, p.z), 0.0f);
    float inter = iw * ih;
    float denom = ((a1 + a2) - inter) + EPSF;
    float q = inter / denom;
    return fminf(fmaxf(q, 0.0f), 1.0f);
}

// ---------- fused prep: coalesced via padded-LDS transpose ----------
// Block = 256 anchors of one batch. LDS stride 257 (+1 pad) kills the
// 15-way conflict ((c*257+a)%32 = (c+a)%32).
__global__ __launch_bounds__(256) void prep_kernel(
        const float* __restrict__ pr,
        const float* __restrict__ ps,
        const float* __restrict__ gt,
        const float* __restrict__ pad,
        float4* __restrict__ pbox,
        float* __restrict__ parea,
        float* __restrict__ psT,
        float4* __restrict__ gbox,
        float4* __restrict__ gtrig,
        float4* __restrict__ ggeom,
        int* __restrict__ cnt,
        int* __restrict__ claim,
        unsigned* __restrict__ maxM,
        unsigned* __restrict__ maxI) {
    __shared__ float lds[CC * 257];
    const int t = threadIdx.x;
    const int b = blockIdx.x / (LL / 256);
    const int j0 = (blockIdx.x % (LL / 256)) * 256;
    const int i = blockIdx.x * 256 + t;           // flat b*LL + j (exact: LL%256==0)

    // Phase A: scores (B,L,C) -> (B,C,L), fully coalesced both sides
    const float* psb = ps + (size_t)(b * LL + j0) * CC;
#pragma unroll
    for (int k = 0; k < CC; ++k) {
        int g = k * 256 + t;                       // 3840 consecutive floats
        lds[(g % CC) * 257 + g / CC] = psb[g];
    }
    __syncthreads();
#pragma unroll
    for (int c = 0; c < CC; ++c)
        psT[((size_t)b * CC + c) * LL + j0 + t] = lds[c * 257 + t];
    __syncthreads();

    // Phase B: pred rboxes, coalesced read of 1280 consecutive floats
    const float* prb = pr + (size_t)(b * LL + j0) * 5;
#pragma unroll
    for (int k = 0; k < 5; ++k) {
        int g = k * 256 + t;
        lds[(g % 5) * 257 + g / 5] = prb[g];
    }
    __syncthreads();
    float cx = lds[0 * 257 + t], cy = lds[1 * 257 + t];
    float w  = lds[2 * 257 + t], h  = lds[3 * 257 + t], r = lds[4 * 257 + t];
    pbox[i]  = rbox_aabb(cx, cy, w, h, r);
    parea[i] = w * h;

    cnt[i] = 0; claim[i] = 0;
    if (i < BB * NGT) {                            // gt prep + per-gt zero-init
        float gcx = gt[i * 5 + 0], gcy = gt[i * 5 + 1];
        float gw  = gt[i * 5 + 2], gh  = gt[i * 5 + 3], gr = gt[i * 5 + 4];
        gbox[i] = rbox_aabb(gcx, gcy, gw, gh, gr);
        float gcr = (float)cos((double)gr);
        float gsr = (float)sin((double)gr);
        gtrig[i] = make_float4(gcr, gsr, gw * gh, pad[i]);
        ggeom[i] = make_float4(gcx, gcy, gw * 0.5f, gh * 0.5f);
        maxM[i] = 0u; maxI[i] = 0u;
    }
}

// ---------- topk phase 1: per-(row,segment) top-13 ----------
// 256-thread blocks = 4 independent waves, one segment each (occupancy fix).
// Per-thread sorted (value desc, index asc) register top-13 over 42 strided
// elements, then 13-round wave-shuffle head merge. Stability == lax.top_k.
__global__ __launch_bounds__(256) void topk_part1(
        const float* __restrict__ psT,
        const int* __restrict__ labels,
        const float* __restrict__ anch,
        const float4* __restrict__ pbox,
        const float* __restrict__ parea,
        const float4* __restrict__ gbox,
        const float4* __restrict__ gtrig,
        const float4* __restrict__ ggeom,
        float* __restrict__ candV,
        int* __restrict__ candJ) {
    int bi = blockIdx.y;                 // b*NGT + i
    int s  = blockIdx.x * 4 + (threadIdx.x >> 6);  // segment (one per wave)
    int t  = threadIdx.x & 63;           // lane
    float4 tg = gtrig[bi];
    if (tg.w == 0.0f) return;            // padded gt (uniform per block)
    int b = bi / NGT;
    float4 g  = gbox[bi];
    float4 gg = ggeom[bi];
    float  a1 = tg.z;
    const float*  srow = psT + ((size_t)b * CC + labels[bi]) * LL;
    const float4* pb   = pbox + (size_t)b * LL;
    const float*  pa   = parea + (size_t)b * LL;
    const float2* an2  = (const float2*)anch;

    float lv[KTOP]; int li[KTOP];
#pragma unroll
    for (int k = 0; k < KTOP; ++k) { lv[k] = -1.0f; li[k] = 0x7fffffff; }

    int base = s * SEGLEN;
    for (int e = t; e < SEGLEN; e += 64) {
        int j = base + e;
        float4 p = pb[j];
        float a2 = pa[j];
        float iou = iou_pair(g, a1, p, a2);
        float2 ap = an2[j];
        float dx = ap.x - gg.x, dy = ap.y - gg.y;
        float xl = dx * tg.x + dy * tg.y;
        float yl = dy * tg.x - dx * tg.y;
        bool ing = (fabsf(xl) <= gg.z) && (fabsf(yl) <= gg.w);
        float i2 = iou * iou;
        float v = ing ? (srow[j] * (i2 * i2 * i2)) : 0.0f;
        if (v > lv[KTOP - 1]) {          // per-thread j ascending -> stable
            lv[KTOP - 1] = v; li[KTOP - 1] = j;
#pragma unroll
            for (int k = KTOP - 1; k > 0; --k) {
                bool sw = lv[k] > lv[k - 1];
                float tv = sw ? lv[k - 1] : lv[k];
                int   ti = sw ? li[k - 1] : li[k];
                lv[k - 1] = sw ? lv[k] : lv[k - 1];
                li[k - 1] = sw ? li[k] : li[k - 1];
                lv[k] = tv; li[k] = ti;
            }
        }
    }

    // wave merge: 13 rounds of butterfly argmax over 64 sorted-list heads
    size_t outIdx = ((size_t)bi * SSEG + s) * KTOP;
    for (int r = 0; r < KTOP; ++r) {
        float ov = lv[0]; int oj = li[0];
#pragma unroll
        for (int off = 32; off > 0; off >>= 1) {
            float v2 = __shfl_xor(ov, off, 64);
            int   j2 = __shfl_xor(oj, off, 64);
            if (v2 > ov || (v2 == ov && j2 < oj)) { ov = v2; oj = j2; }
        }
        if (t == 0) { candV[outIdx + r] = ov; candJ[outIdx + r] = oj; }
        if (li[0] == oj) {               // j unique -> exactly one lane pops
#pragma unroll
            for (int k = 0; k < KTOP - 1; ++k) { lv[k] = lv[k + 1]; li[k] = li[k + 1]; }
            lv[KTOP - 1] = -1.0f; li[KTOP - 1] = 0x7fffffff;
        }
    }
}

// ---------- topk phase 2: merge 8x13 candidates per row -> atomics ----------
__global__ __launch_bounds__(128) void topk_part2(
        const float4* __restrict__ gtrig,
        const float4* __restrict__ ggeom,
        const float* __restrict__ anch,
        const float* __restrict__ candV,
        const int* __restrict__ candJ,
        int* __restrict__ cnt,
        int* __restrict__ claim) {
    int bi = blockIdx.x;
    float4 tg = gtrig[bi];
    if (tg.w == 0.0f) return;
    int b = bi / NGT, i = bi % NGT;
    float4 gg = ggeom[bi];
    int t = threadIdx.x;
    float v = -2.0f; int j = 0x7fffffff;
    if (t < SSEG * KTOP) {
        v = candV[(size_t)bi * SSEG * KTOP + t];
        j = candJ[(size_t)bi * SSEG * KTOP + t];
    }
    __shared__ float sv[2]; __shared__ int si[2];
    for (int r = 0; r < KTOP; ++r) {
        float ov = v; int oj = j;
#pragma unroll
        for (int off = 32; off > 0; off >>= 1) {
            float v2 = __shfl_xor(ov, off, 64);
            int   j2 = __shfl_xor(oj, off, 64);
            if (v2 > ov || (v2 == ov && j2 < oj)) { ov = v2; oj = j2; }
        }
        if ((t & 63) == 0) { sv[t >> 6] = ov; si[t >> 6] = oj; }
        __syncthreads();
        float bv = sv[0]; int bj = si[0];
        if (sv[1] > bv || (sv[1] == bv && si[1] < bj)) { bv = sv[1]; bj = si[1]; }
        if (t == 0) {
            bool in = (bv > 0.0f);       // positive metric implies in_gts
            if (!in) {                   // zero-metric pick: explicit test
                float2 ap = ((const float2*)anch)[bj];
                float dx = ap.x - gg.x, dy = ap.y - gg.y;
                float xl = dx * tg.x + dy * tg.y;
                float yl = dy * tg.x - dx * tg.y;
                in = (fabsf(xl) <= gg.z) && (fabsf(yl) <= gg.w);
            }
            if (in) {
                atomicAdd(&cnt[b * LL + bj], 1);
                atomicMax(&claim[b * LL + bj], i);
            }
        }
        if (j == bj) v = -2.0f;          // consume winner (j unique per row)
        __syncthreads();
    }
}

// ---------- resolve: assign one gt (or none) per anchor; per-gt maxes ----------
__global__ void resolve_kernel(const float* __restrict__ psT,
                               const int* __restrict__ labels,
                               const float4* __restrict__ pbox,
                               const float* __restrict__ parea,
                               const float4* __restrict__ gbox,
                               const float4* __restrict__ gtrig,
                               const int* __restrict__ cnt,
                               const int* __restrict__ claim,
                               int* __restrict__ assigned,
                               float* __restrict__ aMetric,
                               unsigned* __restrict__ maxM,
                               unsigned* __restrict__ maxI) {
    __shared__ float4 sB[NGT];
    __shared__ float  sA[NGT];
    int b = blockIdx.y, t = threadIdx.x;
    if (t < NGT) { sB[t] = gbox[b * NGT + t]; sA[t] = gtrig[b * NGT + t].z; }
    __syncthreads();
    int j = blockIdx.x * blockDim.x + t;
    if (j >= LL) return;
    int p = b * LL + j;
    int c = cnt[p];
    if (c == 0) { assigned[p] = -1; aMetric[p] = 0.0f; return; }
    float4 pb = pbox[p];
    float a2 = parea[p];
    int a; float iouv;
    if (c == 1) {
        a = claim[p];
        iouv = iou_pair(sB[a], sA[a], pb, a2);
    } else {
        float best = -1.0f; int bi = 0;
        for (int i = 0; i < NGT; ++i) {
            float v = iou_pair(sB[i], sA[i], pb, a2);
            if (v > best) { best = v; bi = i; }       // ties -> lowest index
        }
        a = bi; iouv = best;
    }
    float sc = psT[((size_t)b * CC + labels[b * NGT + a]) * LL + j];
    float i2 = iouv * iouv;
    float m = sc * (i2 * i2 * i2);
    assigned[p] = a;
    aMetric[p] = m;
    atomicMax(&maxM[b * NGT + a], __float_as_uint(m));
    atomicMax(&maxI[b * NGT + a], __float_as_uint(iouv));
}

// ---------- finalize: all 5 outputs; strided regions via LDS transpose ----------
__global__ __launch_bounds__(256) void finalize_kernel(
        const float* __restrict__ gt,
        const int* __restrict__ labels,
        const int* __restrict__ crowd,
        const int* __restrict__ assigned,
        const float* __restrict__ aMetric,
        const unsigned* __restrict__ maxM,
        const unsigned* __restrict__ maxI,
        float* __restrict__ out) {
    __shared__ float lds[CC * 257];
    const int t = threadIdx.x;
    const int b = blockIdx.x / (LL / 256);
    const int j0 = (blockIdx.x % (LL / 256)) * 256;
    const int p = blockIdx.x * 256 + t;
    const size_t O0 = 0;
    const size_t O1 = (size_t)BB * LL;
    const size_t O2 = O1 + (size_t)BB * LL * 5;
    const size_t O3 = O2 + (size_t)BB * LL * CC;
    const size_t O4 = O3 + (size_t)BB * LL;

    int a = assigned[p];
    bool pos = (a >= 0);
    int idx = pos ? a : 0;
    int lab = labels[b * NGT + idx];
    int cw  = crowd[b * NGT + idx];
    out[O0 + p] = pos ? (float)lab : (float)BGI;
    out[O3 + p] = (float)idx;
    out[O4 + p] = (float)cw;
    float per = 0.0f;
    if (pos) {
        float mm = __uint_as_float(maxM[b * NGT + a]);
        float mi = __uint_as_float(maxI[b * NGT + a]);
        per = aMetric[p] / (mm + EPSF) * mi;
    }

    // assigned_scores (stride-15) via LDS transpose
    float keep = (pos && cw == 0) ? per : 0.0f;
#pragma unroll
    for (int c = 0; c < CC; ++c)
        lds[c * 257 + t] = (c == lab) ? keep : 0.0f;
    __syncthreads();
    float* o2 = out + O2 + (size_t)(b * LL + j0) * CC;
#pragma unroll
    for (int k = 0; k < CC; ++k) {
        int g = k * 256 + t;
        o2[g] = lds[(g % CC) * 257 + g / CC];
    }
    __syncthreads();

    // assigned_rboxes (stride-5) via LDS transpose
    const float* gb = gt + (size_t)(b * NGT + idx) * 5;
#pragma unroll
    for (int k = 0; k < 5; ++k)
        lds[k * 257 + t] = gb[k];
    __syncthreads();
    float* o1 = out + O1 + (size_t)(b * LL + j0) * 5;
#pragma unroll
    for (int k = 0; k < 5; ++k) {
        int g = k * 256 + t;
        o1[g] = lds[(g % 5) * 257 + g / 5];
    }
}

extern "C" void kernel_launch(void* const* d_in, const int* in_sizes, int n_in,
                              void* d_out, int out_size, void* d_ws, size_t ws_size,
                              hipStream_t stream) {
    const float* pred_scores = (const float*)d_in[0];
    const float* pred_rboxes = (const float*)d_in[1];
    const float* anchor_pts  = (const float*)d_in[2];
    const int*   gt_labels   = (const int*)d_in[3];
    const float* gt_bboxes   = (const float*)d_in[4];
    // d_in[5] = gt_poses (unused)
    const int*   gt_crowd    = (const int*)d_in[6];
    const float* pad_gt      = (const float*)d_in[7];
    float* out = (float*)d_out;

    char* ws = (char*)d_ws;
    size_t off = 0;
    auto alloc = [&](size_t bytes) {
        void* pp = ws + off;
        off += (bytes + 255) & ~(size_t)255;
        return pp;
    };
    float*  psT   = (float*)alloc((size_t)BB * CC * LL * 4);
    float4* pbox  = (float4*)alloc((size_t)BB * LL * 16);
    float*  parea = (float*)alloc((size_t)BB * LL * 4);
    float4* gbox  = (float4*)alloc((size_t)BB * NGT * 16);
    float4* gtrig = (float4*)alloc((size_t)BB * NGT * 16);
    float4* ggeom = (float4*)alloc((size_t)BB * NGT * 16);
    int* cnt        = (int*)alloc((size_t)BB * LL * 4);
    int* claim      = (int*)alloc((size_t)BB * LL * 4);
    unsigned* maxM  = (unsigned*)alloc((size_t)BB * NGT * 4);
    unsigned* maxI  = (unsigned*)alloc((size_t)BB * NGT * 4);
    int*   assigned = (int*)alloc((size_t)BB * LL * 4);
    float* aMetric  = (float*)alloc((size_t)BB * LL * 4);
    float* candV    = (float*)alloc((size_t)BB * NGT * SSEG * KTOP * 4);
    int*   candJ    = (int*)alloc((size_t)BB * NGT * SSEG * KTOP * 4);

    prep_kernel<<<dim3(BB * LL / 256), dim3(256), 0, stream>>>(
        pred_rboxes, pred_scores, gt_bboxes, pad_gt,
        pbox, parea, psT, gbox, gtrig, ggeom, cnt, claim, maxM, maxI);
    topk_part1<<<dim3(SSEG / 4, BB * NGT), dim3(256), 0, stream>>>(
        psT, gt_labels, anchor_pts, pbox, parea, gbox, gtrig, ggeom, candV, candJ);
    topk_part2<<<dim3(BB * NGT), dim3(128), 0, stream>>>(
        gtrig, ggeom, anchor_pts, candV, candJ, cnt, claim);
    resolve_kernel<<<dim3(LL / 256, BB), dim3(256), 0, stream>>>(
        psT, gt_labels, pbox, parea, gbox, gtrig, cnt, claim,
        assigned, aMetric, maxM, maxI);
    finalize_kernel<<<dim3(BB * LL / 256), dim3(256), 0, stream>>>(
        gt_bboxes, gt_labels, gt_crowd, assigned, aMetric, maxM, maxI, out);
}

// Round 5
// 153.925 us; speedup vs baseline: 1.4355x; 1.4156x over previous
//
#include <hip/hip_runtime.h>
#include <math.h>

#pragma clang fp contract(off)

#define BB   8
#define NGT  60
#define LL   21504
#define CC   15
#define KTOP 13
#define BGI  15
#define EPSF 1e-9f
#define SSEG 16
#define SEGLEN (LL / SSEG)   // 1344 -> 21 elements per lane

typedef unsigned long long u64;

// branchless descending compare-swap: ensures a >= b afterwards
#define CS(a, b) { u64 _hi = (b > a) ? b : a; u64 _lo = (b > a) ? a : b; a = _hi; b = _lo; }

// AABB of rotated box, replicating reference _box_min_max op order.
__device__ __forceinline__ float4 rbox_aabb(float cx, float cy, float w, float h, float r) {
    float cr = (float)cos((double)r);
    float sr = (float)sin((double)r);
    float dx = (w * 0.5f) * cr;
    float dy = (h * 0.5f) * sr;
    float xs[4] = {cx - dx, cx + dx, cx + dx, cx - dx};
    float ys[4] = {cy - dy, cy - dy, cy + dy, cy + dy};
    float mnx = 1e30f, mxx = -1e30f, mny = 1e30f, mxy = -1e30f;
#pragma unroll
    for (int k = 0; k < 4; ++k) {
        float tx = xs[k] - cx, ty = ys[k] - cy;
        float xr = (cx + tx * cr) - ty * sr;
        float yr = (cy + tx * sr) + ty * cr;
        mnx = fminf(mnx, xr); mxx = fmaxf(mxx, xr);
        mny = fminf(mny, yr); mxy = fmaxf(mxy, yr);
    }
    return make_float4(mnx, mxx, mny, mxy);
}

__device__ __forceinline__ float iou_pair(float4 g, float a1, float4 p, float a2) {
    float iw = fmaxf(fminf(g.y, p.y) - fmaxf(g.x, p.x), 0.0f);
    float ih = fmaxf(fminf(g.w, p.w) - fmaxf(g.z, p.z), 0.0f);
    float inter = iw * ih;
    float denom = ((a1 + a2) - inter) + EPSF;
    float q = inter / denom;
    return fminf(fmaxf(q, 0.0f), 1.0f);
}

// ---------- fused prep: coalesced via padded-LDS transpose ----------
__global__ __launch_bounds__(256) void prep_kernel(
        const float* __restrict__ pr,
        const float* __restrict__ ps,
        const float* __restrict__ gt,
        const float* __restrict__ pad,
        float4* __restrict__ pbox,
        float* __restrict__ parea,
        float* __restrict__ psT,
        float4* __restrict__ gbox,
        float4* __restrict__ gtrig,
        float4* __restrict__ ggeom,
        int* __restrict__ cnt,
        int* __restrict__ claim,
        unsigned* __restrict__ maxM,
        unsigned* __restrict__ maxI) {
    __shared__ float lds[CC * 257];
    const int t = threadIdx.x;
    const int b = blockIdx.x / (LL / 256);
    const int j0 = (blockIdx.x % (LL / 256)) * 256;
    const int i = blockIdx.x * 256 + t;

    // scores (B,L,C) -> (B,C,L), coalesced both sides, +1-padded LDS
    const float* psb = ps + (size_t)(b * LL + j0) * CC;
#pragma unroll
    for (int k = 0; k < CC; ++k) {
        int g = k * 256 + t;
        lds[(g % CC) * 257 + g / CC] = psb[g];
    }
    __syncthreads();
#pragma unroll
    for (int c = 0; c < CC; ++c)
        psT[((size_t)b * CC + c) * LL + j0 + t] = lds[c * 257 + t];
    __syncthreads();

    // pred rboxes: coalesced read of 1280 consecutive floats
    const float* prb = pr + (size_t)(b * LL + j0) * 5;
#pragma unroll
    for (int k = 0; k < 5; ++k) {
        int g = k * 256 + t;
        lds[(g % 5) * 257 + g / 5] = prb[g];
    }
    __syncthreads();
    float cx = lds[0 * 257 + t], cy = lds[1 * 257 + t];
    float w  = lds[2 * 257 + t], h  = lds[3 * 257 + t], r = lds[4 * 257 + t];
    pbox[i]  = rbox_aabb(cx, cy, w, h, r);
    parea[i] = w * h;

    cnt[i] = 0; claim[i] = 0;
    if (i < BB * NGT) {
        float gcx = gt[i * 5 + 0], gcy = gt[i * 5 + 1];
        float gw  = gt[i * 5 + 2], gh  = gt[i * 5 + 3], gr = gt[i * 5 + 4];
        gbox[i] = rbox_aabb(gcx, gcy, gw, gh, gr);
        float gcr = (float)cos((double)gr);
        float gsr = (float)sin((double)gr);
        gtrig[i] = make_float4(gcr, gsr, gw * gh, pad[i]);
        ggeom[i] = make_float4(gcx, gcy, gw * 0.5f, gh * 0.5f);
        maxM[i] = 0u; maxI[i] = 0u;
    }
}

// ---------- topk phase 1: per-(row,segment) top-13, spill-free ----------
// Key = (float_bits(v) << 32) | ~j  -> single u64 descending compare gives
// (value desc, index asc), exactly jax.lax.top_k's stable order (v >= 0).
// 13 NAMED u64 registers (no arrays -> no scratch spill). Each lane scans
// 21 elements; 13-round wave-shuffle head merge emits segment top-13.
__global__ __launch_bounds__(256) void topk_part1(
        const float* __restrict__ psT,
        const int* __restrict__ labels,
        const float* __restrict__ anch,
        const float4* __restrict__ pbox,
        const float* __restrict__ parea,
        const float4* __restrict__ gbox,
        const float4* __restrict__ gtrig,
        const float4* __restrict__ ggeom,
        u64* __restrict__ candK) {
    int bi = blockIdx.y;                 // b*NGT + i
    int s  = blockIdx.x * 4 + (threadIdx.x >> 6);  // one segment per wave
    int t  = threadIdx.x & 63;
    float4 tg = gtrig[bi];
    if (tg.w == 0.0f) return;            // padded gt (uniform per block)
    int b = bi / NGT;
    float4 g  = gbox[bi];
    float4 gg = ggeom[bi];
    float  a1 = tg.z;
    const float*  srow = psT + ((size_t)b * CC + labels[bi]) * LL;
    const float4* pb   = pbox + (size_t)b * LL;
    const float*  pa   = parea + (size_t)b * LL;
    const float2* an2  = (const float2*)anch;

    u64 k0 = 0, k1 = 0, k2 = 0, k3 = 0, k4 = 0, k5 = 0, k6 = 0,
        k7 = 0, k8 = 0, k9 = 0, k10 = 0, k11 = 0, k12 = 0;

    int base = s * SEGLEN;
    for (int e = t; e < SEGLEN; e += 64) {
        int j = base + e;
        float2 ap = an2[j];
        float dx = ap.x - gg.x, dy = ap.y - gg.y;
        float xl = dx * tg.x + dy * tg.y;
        float yl = dy * tg.x - dx * tg.y;
        bool ing = (fabsf(xl) <= gg.z) && (fabsf(yl) <= gg.w);
        float v = 0.0f;
        if (__ballot(ing)) {             // wave-uniform fast-path skip
            float4 p = pb[j];
            float a2 = pa[j];
            float iou = iou_pair(g, a1, p, a2);
            float i2 = iou * iou;
            v = ing ? (srow[j] * (i2 * i2 * i2)) : 0.0f;
        }
        u64 key = ((u64)__float_as_uint(v) << 32) | (unsigned)(~j);
        if (key > k12) {                 // insert + bubble (branchless chain)
            k12 = key;
            CS(k11, k12); CS(k10, k11); CS(k9, k10); CS(k8, k9);
            CS(k7, k8);   CS(k6, k7);   CS(k5, k6);  CS(k4, k5);
            CS(k3, k4);   CS(k2, k3);   CS(k1, k2);  CS(k0, k1);
        }
    }

    // 13-round butterfly merge over the 64 sorted-list heads
    size_t outIdx = ((size_t)bi * SSEG + s) * KTOP;
    for (int r = 0; r < KTOP; ++r) {
        u64 ov = k0;
#pragma unroll
        for (int off = 32; off > 0; off >>= 1) {
            u64 v2 = __shfl_xor(ov, off, 64);
            if (v2 > ov) ov = v2;
        }
        if (t == 0) candK[outIdx + r] = ov;
        if (k0 == ov) {                  // keys unique -> exactly one lane pops
            k0 = k1; k1 = k2; k2 = k3; k3 = k4; k4 = k5; k5 = k6; k6 = k7;
            k7 = k8; k8 = k9; k9 = k10; k10 = k11; k11 = k12; k12 = 0;
        }
    }
}

// ---------- topk phase 2: merge 16x13 candidates per row -> atomics ----------
__global__ __launch_bounds__(256) void topk_part2(
        const float4* __restrict__ gtrig,
        const float4* __restrict__ ggeom,
        const float* __restrict__ anch,
        const u64* __restrict__ candK,
        int* __restrict__ cnt,
        int* __restrict__ claim) {
    int bi = blockIdx.x;
    float4 tg = gtrig[bi];
    if (tg.w == 0.0f) return;
    int b = bi / NGT, i = bi % NGT;
    float4 gg = ggeom[bi];
    int t = threadIdx.x;
    u64 myk = 0;
    if (t < SSEG * KTOP)
        myk = candK[(size_t)bi * SSEG * KTOP + t];
    __shared__ u64 sk[4];
    __shared__ u64 swin;
    for (int r = 0; r < KTOP; ++r) {
        u64 ov = myk;
#pragma unroll
        for (int off = 32; off > 0; off >>= 1) {
            u64 v2 = __shfl_xor(ov, off, 64);
            if (v2 > ov) ov = v2;
        }
        if ((t & 63) == 0) sk[t >> 6] = ov;
        __syncthreads();
        if (t == 0) {
            u64 bk = sk[0];
#pragma unroll
            for (int k = 1; k < 4; ++k) if (sk[k] > bk) bk = sk[k];
            swin = bk;
            unsigned vb = (unsigned)(bk >> 32);
            int j = (int)(~(unsigned)bk);
            bool in = (vb != 0);         // v > 0 implies in_gts
            if (!in) {                   // zero-metric pick: explicit test
                float2 ap = ((const float2*)anch)[j];
                float dx = ap.x - gg.x, dy = ap.y - gg.y;
                float xl = dx * tg.x + dy * tg.y;
                float yl = dy * tg.x - dx * tg.y;
                in = (fabsf(xl) <= gg.z) && (fabsf(yl) <= gg.w);
            }
            if (in) {
                atomicAdd(&cnt[b * LL + j], 1);
                atomicMax(&claim[b * LL + j], i);
            }
        }
        __syncthreads();
        if (myk == swin) myk = 0;        // consume winner (keys unique)
    }
}

// ---------- resolve: assign one gt (or none) per anchor; per-gt maxes ----------
__global__ void resolve_kernel(const float* __restrict__ psT,
                               const int* __restrict__ labels,
                               const float4* __restrict__ pbox,
                               const float* __restrict__ parea,
                               const float4* __restrict__ gbox,
                               const float4* __restrict__ gtrig,
                               const int* __restrict__ cnt,
                               const int* __restrict__ claim,
                               int* __restrict__ assigned,
                               float* __restrict__ aMetric,
                               unsigned* __restrict__ maxM,
                               unsigned* __restrict__ maxI) {
    __shared__ float4 sB[NGT];
    __shared__ float  sA[NGT];
    int b = blockIdx.y, t = threadIdx.x;
    if (t < NGT) { sB[t] = gbox[b * NGT + t]; sA[t] = gtrig[b * NGT + t].z; }
    __syncthreads();
    int j = blockIdx.x * blockDim.x + t;
    if (j >= LL) return;
    int p = b * LL + j;
    int c = cnt[p];
    if (c == 0) { assigned[p] = -1; aMetric[p] = 0.0f; return; }
    float4 pb = pbox[p];
    float a2 = parea[p];
    int a; float iouv;
    if (c == 1) {
        a = claim[p];
        iouv = iou_pair(sB[a], sA[a], pb, a2);
    } else {
        float best = -1.0f; int bi = 0;
        for (int i = 0; i < NGT; ++i) {
            float v = iou_pair(sB[i], sA[i], pb, a2);
            if (v > best) { best = v; bi = i; }       // ties -> lowest index
        }
        a = bi; iouv = best;
    }
    float sc = psT[((size_t)b * CC + labels[b * NGT + a]) * LL + j];
    float i2 = iouv * iouv;
    float m = sc * (i2 * i2 * i2);
    assigned[p] = a;
    aMetric[p] = m;
    atomicMax(&maxM[b * NGT + a], __float_as_uint(m));
    atomicMax(&maxI[b * NGT + a], __float_as_uint(iouv));
}

// ---------- finalize: all 5 outputs; strided regions via LDS transpose ----------
__global__ __launch_bounds__(256) void finalize_kernel(
        const float* __restrict__ gt,
        const int* __restrict__ labels,
        const int* __restrict__ crowd,
        const int* __restrict__ assigned,
        const float* __restrict__ aMetric,
        const unsigned* __restrict__ maxM,
        const unsigned* __restrict__ maxI,
        float* __restrict__ out) {
    __shared__ float lds[CC * 257];
    const int t = threadIdx.x;
    const int b = blockIdx.x / (LL / 256);
    const int j0 = (blockIdx.x % (LL / 256)) * 256;
    const int p = blockIdx.x * 256 + t;
    const size_t O0 = 0;
    const size_t O1 = (size_t)BB * LL;
    const size_t O2 = O1 + (size_t)BB * LL * 5;
    const size_t O3 = O2 + (size_t)BB * LL * CC;
    const size_t O4 = O3 + (size_t)BB * LL;

    int a = assigned[p];
    bool pos = (a >= 0);
    int idx = pos ? a : 0;
    int lab = labels[b * NGT + idx];
    int cw  = crowd[b * NGT + idx];
    out[O0 + p] = pos ? (float)lab : (float)BGI;
    out[O3 + p] = (float)idx;
    out[O4 + p] = (float)cw;
    float per = 0.0f;
    if (pos) {
        float mm = __uint_as_float(maxM[b * NGT + a]);
        float mi = __uint_as_float(maxI[b * NGT + a]);
        per = aMetric[p] / (mm + EPSF) * mi;
    }

    // assigned_scores (stride-15) via LDS transpose
    float keep = (pos && cw == 0) ? per : 0.0f;
#pragma unroll
    for (int c = 0; c < CC; ++c)
        lds[c * 257 + t] = (c == lab) ? keep : 0.0f;
    __syncthreads();
    float* o2 = out + O2 + (size_t)(b * LL + j0) * CC;
#pragma unroll
    for (int k = 0; k < CC; ++k) {
        int g = k * 256 + t;
        o2[g] = lds[(g % CC) * 257 + g / CC];
    }
    __syncthreads();

    // assigned_rboxes (stride-5) via LDS transpose
    const float* gb = gt + (size_t)(b * NGT + idx) * 5;
#pragma unroll
    for (int k = 0; k < 5; ++k)
        lds[k * 257 + t] = gb[k];
    __syncthreads();
    float* o1 = out + O1 + (size_t)(b * LL + j0) * 5;
#pragma unroll
    for (int k = 0; k < 5; ++k) {
        int g = k * 256 + t;
        o1[g] = lds[(g % 5) * 257 + g / 5];
    }
}

extern "C" void kernel_launch(void* const* d_in, const int* in_sizes, int n_in,
                              void* d_out, int out_size, void* d_ws, size_t ws_size,
                              hipStream_t stream) {
    const float* pred_scores = (const float*)d_in[0];
    const float* pred_rboxes = (const float*)d_in[1];
    const float* anchor_pts  = (const float*)d_in[2];
    const int*   gt_labels   = (const int*)d_in[3];
    const float* gt_bboxes   = (const float*)d_in[4];
    // d_in[5] = gt_poses (unused)
    const int*   gt_crowd    = (const int*)d_in[6];
    const float* pad_gt      = (const float*)d_in[7];
    float* out = (float*)d_out;

    char* ws = (char*)d_ws;
    size_t off = 0;
    auto alloc = [&](size_t bytes) {
        void* pp = ws + off;
        off += (bytes + 255) & ~(size_t)255;
        return pp;
    };
    float*  psT   = (float*)alloc((size_t)BB * CC * LL * 4);
    float4* pbox  = (float4*)alloc((size_t)BB * LL * 16);
    float*  parea = (float*)alloc((size_t)BB * LL * 4);
    float4* gbox  = (float4*)alloc((size_t)BB * NGT * 16);
    float4* gtrig = (float4*)alloc((size_t)BB * NGT * 16);
    float4* ggeom = (float4*)alloc((size_t)BB * NGT * 16);
    int* cnt        = (int*)alloc((size_t)BB * LL * 4);
    int* claim      = (int*)alloc((size_t)BB * LL * 4);
    unsigned* maxM  = (unsigned*)alloc((size_t)BB * NGT * 4);
    unsigned* maxI  = (unsigned*)alloc((size_t)BB * NGT * 4);
    int*   assigned = (int*)alloc((size_t)BB * LL * 4);
    float* aMetric  = (float*)alloc((size_t)BB * LL * 4);
    u64*   candK    = (u64*)alloc((size_t)BB * NGT * SSEG * KTOP * 8);

    prep_kernel<<<dim3(BB * LL / 256), dim3(256), 0, stream>>>(
        pred_rboxes, pred_scores, gt_bboxes, pad_gt,
        pbox, parea, psT, gbox, gtrig, ggeom, cnt, claim, maxM, maxI);
    topk_part1<<<dim3(SSEG / 4, BB * NGT), dim3(256), 0, stream>>>(
        psT, gt_labels, anchor_pts, pbox, parea, gbox, gtrig, ggeom, candK);
    topk_part2<<<dim3(BB * NGT), dim3(256), 0, stream>>>(
        gtrig, ggeom, anchor_pts, candK, cnt, claim);
    resolve_kernel<<<dim3(LL / 256, BB), dim3(256), 0, stream>>>(
        psT, gt_labels, pbox, parea, gbox, gtrig, cnt, claim,
        assigned, aMetric, maxM, maxI);
    finalize_kernel<<<dim3(BB * LL / 256), dim3(256), 0, stream>>>(
        gt_bboxes, gt_labels, gt_crowd, assigned, aMetric, maxM, maxI, out);
}

// Round 7
// 150.303 us; speedup vs baseline: 1.4701x; 1.0241x over previous
//
#include <hip/hip_runtime.h>
#include <math.h>

#pragma clang fp contract(off)

#define BB   8
#define NGT  60
#define LL   21504
#define CC   15
#define KTOP 13
#define BGI  15
#define EPSF 1e-9f
#define SSEG 16
#define SEGLEN (LL / SSEG)   // 1344 -> 21 elements per lane

typedef unsigned long long u64;

// branchless descending compare-swap: ensures a >= b afterwards
#define CS(a, b) { u64 _hi = (b > a) ? b : a; u64 _lo = (b > a) ? a : b; a = _hi; b = _lo; }

// AABB of rotated box, replicating reference _box_min_max op order.
__device__ __forceinline__ float4 rbox_aabb(float cx, float cy, float w, float h, float r) {
    float cr = (float)cos((double)r);
    float sr = (float)sin((double)r);
    float dx = (w * 0.5f) * cr;
    float dy = (h * 0.5f) * sr;
    float xs[4] = {cx - dx, cx + dx, cx + dx, cx - dx};
    float ys[4] = {cy - dy, cy - dy, cy + dy, cy + dy};
    float mnx = 1e30f, mxx = -1e30f, mny = 1e30f, mxy = -1e30f;
#pragma unroll
    for (int k = 0; k < 4; ++k) {
        float tx = xs[k] - cx, ty = ys[k] - cy;
        float xr = (cx + tx * cr) - ty * sr;
        float yr = (cy + tx * sr) + ty * cr;
        mnx = fminf(mnx, xr); mxx = fmaxf(mxx, xr);
        mny = fminf(mny, yr); mxy = fmaxf(mxy, yr);
    }
    return make_float4(mnx, mxx, mny, mxy);
}

__device__ __forceinline__ float iou_pair(float4 g, float a1, float4 p, float a2) {
    float iw = fmaxf(fminf(g.y, p.y) - fmaxf(g.x, p.x), 0.0f);
    float ih = fmaxf(fminf(g.w, p.w) - fmaxf(g.z, p.z), 0.0f);
    float inter = iw * ih;
    float denom = ((a1 + a2) - inter) + EPSF;
    float q = inter / denom;
    return fminf(fmaxf(q, 0.0f), 1.0f);
}

// ---------- prep: pred boxes (LDS-coalesced), gt state, zero-init ----------
// No score transpose: scores are consumed sparsely, direct reads are cheaper.
__global__ __launch_bounds__(256) void prep_kernel(
        const float* __restrict__ pr,
        const float* __restrict__ gt,
        const float* __restrict__ pad,
        float4* __restrict__ pbox,
        float* __restrict__ parea,
        float4* __restrict__ gbox,
        float4* __restrict__ gtrig,
        float4* __restrict__ ggeom,
        int* __restrict__ cnt,
        int* __restrict__ claim,
        unsigned* __restrict__ maxM,
        unsigned* __restrict__ maxI) {
    __shared__ float lds[5 * 257];
    const int t = threadIdx.x;
    const int b = blockIdx.x / (LL / 256);
    const int j0 = (blockIdx.x % (LL / 256)) * 256;
    const int i = blockIdx.x * 256 + t;

    // pred rboxes: coalesced read of 1280 consecutive floats, +1-pad LDS
    const float* prb = pr + (size_t)(b * LL + j0) * 5;
#pragma unroll
    for (int k = 0; k < 5; ++k) {
        int g = k * 256 + t;
        lds[(g % 5) * 257 + g / 5] = prb[g];
    }
    __syncthreads();
    float cx = lds[0 * 257 + t], cy = lds[1 * 257 + t];
    float w  = lds[2 * 257 + t], h  = lds[3 * 257 + t], r = lds[4 * 257 + t];
    pbox[i]  = rbox_aabb(cx, cy, w, h, r);
    parea[i] = w * h;

    cnt[i] = 0; claim[i] = 0;
    if (i < BB * NGT) {
        float gcx = gt[i * 5 + 0], gcy = gt[i * 5 + 1];
        float gw  = gt[i * 5 + 2], gh  = gt[i * 5 + 3], gr = gt[i * 5 + 4];
        gbox[i] = rbox_aabb(gcx, gcy, gw, gh, gr);
        float gcr = (float)cos((double)gr);
        float gsr = (float)sin((double)gr);
        gtrig[i] = make_float4(gcr, gsr, gw * gh, pad[i]);
        ggeom[i] = make_float4(gcx, gcy, gw * 0.5f, gh * 0.5f);
        maxM[i] = 0u; maxI[i] = 0u;
    }
}

// ---------- topk phase 1: per-(row,segment) top-13, spill-free ----------
// Key = (float_bits(v) << 32) | ~j  -> single u64 descending compare gives
// (value desc, index asc), exactly jax.lax.top_k's stable order (v >= 0).
// 13 NAMED u64 registers (no arrays -> no scratch spill). Each lane scans
// 21 elements; 13-round wave-shuffle head merge emits segment top-13.
__global__ __launch_bounds__(256) void topk_part1(
        const float* __restrict__ ps,
        const int* __restrict__ labels,
        const float* __restrict__ anch,
        const float4* __restrict__ pbox,
        const float* __restrict__ parea,
        const float4* __restrict__ gbox,
        const float4* __restrict__ gtrig,
        const float4* __restrict__ ggeom,
        u64* __restrict__ candK) {
    int bi = blockIdx.y;                 // b*NGT + i
    int s  = blockIdx.x * 4 + (threadIdx.x >> 6);  // one segment per wave
    int t  = threadIdx.x & 63;
    float4 tg = gtrig[bi];
    if (tg.w == 0.0f) return;            // padded gt (uniform per block)
    int b = bi / NGT;
    float4 g  = gbox[bi];
    float4 gg = ggeom[bi];
    float  a1 = tg.z;
    const float*  srow = ps + (size_t)b * LL * CC + labels[bi];  // stride CC
    const float4* pb   = pbox + (size_t)b * LL;
    const float*  pa   = parea + (size_t)b * LL;
    const float2* an2  = (const float2*)anch;

    u64 k0 = 0, k1 = 0, k2 = 0, k3 = 0, k4 = 0, k5 = 0, k6 = 0,
        k7 = 0, k8 = 0, k9 = 0, k10 = 0, k11 = 0, k12 = 0;

    int base = s * SEGLEN;
    for (int e = t; e < SEGLEN; e += 64) {
        int j = base + e;
        float2 ap = an2[j];
        float dx = ap.x - gg.x, dy = ap.y - gg.y;
        float xl = dx * tg.x + dy * tg.y;
        float yl = dy * tg.x - dx * tg.y;
        bool ing = (fabsf(xl) <= gg.z) && (fabsf(yl) <= gg.w);
        float v = 0.0f;
        if (__ballot(ing)) {             // wave-uniform fast-path skip
            float4 p = pb[j];
            float a2 = pa[j];
            float iou = iou_pair(g, a1, p, a2);
            float i2 = iou * iou;
            v = ing ? (srow[(size_t)j * CC] * (i2 * i2 * i2)) : 0.0f;
        }
        u64 key = ((u64)__float_as_uint(v) << 32) | (unsigned)(~j);
        if (key > k12) {                 // insert + bubble (branchless chain)
            k12 = key;
            CS(k11, k12); CS(k10, k11); CS(k9, k10); CS(k8, k9);
            CS(k7, k8);   CS(k6, k7);   CS(k5, k6);  CS(k4, k5);
            CS(k3, k4);   CS(k2, k3);   CS(k1, k2);  CS(k0, k1);
        }
    }

    // 13-round butterfly merge over the 64 sorted-list heads
    size_t outIdx = ((size_t)bi * SSEG + s) * KTOP;
    for (int r = 0; r < KTOP; ++r) {
        u64 ov = k0;
#pragma unroll
        for (int off = 32; off > 0; off >>= 1) {
            u64 v2 = __shfl_xor(ov, off, 64);
            if (v2 > ov) ov = v2;
        }
        if (t == 0) candK[outIdx + r] = ov;
        if (k0 == ov) {                  // keys unique -> exactly one lane pops
            k0 = k1; k1 = k2; k2 = k3; k3 = k4; k4 = k5; k5 = k6; k6 = k7;
            k7 = k8; k8 = k9; k9 = k10; k10 = k11; k11 = k12; k12 = 0;
        }
    }
}

// ---------- topk phase 2: merge 16x13 candidates per row -> atomics ----------
__global__ __launch_bounds__(256) void topk_part2(
        const float4* __restrict__ gtrig,
        const float4* __restrict__ ggeom,
        const float* __restrict__ anch,
        const u64* __restrict__ candK,
        int* __restrict__ cnt,
        int* __restrict__ claim) {
    int bi = blockIdx.x;
    float4 tg = gtrig[bi];
    if (tg.w == 0.0f) return;
    int b = bi / NGT, i = bi % NGT;
    float4 gg = ggeom[bi];
    int t = threadIdx.x;
    u64 myk = 0;
    if (t < SSEG * KTOP)
        myk = candK[(size_t)bi * SSEG * KTOP + t];
    __shared__ u64 sk[4];
    __shared__ u64 swin;
    for (int r = 0; r < KTOP; ++r) {
        u64 ov = myk;
#pragma unroll
        for (int off = 32; off > 0; off >>= 1) {
            u64 v2 = __shfl_xor(ov, off, 64);
            if (v2 > ov) ov = v2;
        }
        if ((t & 63) == 0) sk[t >> 6] = ov;
        __syncthreads();
        if (t == 0) {
            u64 bk = sk[0];
#pragma unroll
            for (int k = 1; k < 4; ++k) if (sk[k] > bk) bk = sk[k];
            swin = bk;
            unsigned vb = (unsigned)(bk >> 32);
            int j = (int)(~(unsigned)bk);
            bool in = (vb != 0);         // v > 0 implies in_gts
            if (!in) {                   // zero-metric pick: explicit test
                float2 ap = ((const float2*)anch)[j];
                float dx = ap.x - gg.x, dy = ap.y - gg.y;
                float xl = dx * tg.x + dy * tg.y;
                float yl = dy * tg.x - dx * tg.y;
                in = (fabsf(xl) <= gg.z) && (fabsf(yl) <= gg.w);
            }
            if (in) {
                atomicAdd(&cnt[b * LL + j], 1);
                atomicMax(&claim[b * LL + j], i);
            }
        }
        __syncthreads();
        if (myk == swin) myk = 0;        // consume winner (keys unique)
    }
}

// ---------- resolve: assign one gt (or none) per anchor; per-gt maxes ----------
__global__ void resolve_kernel(const float* __restrict__ ps,
                               const int* __restrict__ labels,
                               const float4* __restrict__ pbox,
                               const float* __restrict__ parea,
                               const float4* __restrict__ gbox,
                               const float4* __restrict__ gtrig,
                               const int* __restrict__ cnt,
                               const int* __restrict__ claim,
                               int* __restrict__ assigned,
                               float* __restrict__ aMetric,
                               unsigned* __restrict__ maxM,
                               unsigned* __restrict__ maxI) {
    __shared__ float4 sB[NGT];
    __shared__ float  sA[NGT];
    int b = blockIdx.y, t = threadIdx.x;
    if (t < NGT) { sB[t] = gbox[b * NGT + t]; sA[t] = gtrig[b * NGT + t].z; }
    __syncthreads();
    int j = blockIdx.x * blockDim.x + t;
    if (j >= LL) return;
    int p = b * LL + j;
    int c = cnt[p];
    if (c == 0) { assigned[p] = -1; aMetric[p] = 0.0f; return; }
    float4 pb = pbox[p];
    float a2 = parea[p];
    int a; float iouv;
    if (c == 1) {
        a = claim[p];
        iouv = iou_pair(sB[a], sA[a], pb, a2);
    } else {
        float best = -1.0f; int bi = 0;
        for (int i = 0; i < NGT; ++i) {
            float v = iou_pair(sB[i], sA[i], pb, a2);
            if (v > best) { best = v; bi = i; }       // ties -> lowest index
        }
        a = bi; iouv = best;
    }
    float sc = ps[(size_t)p * CC + labels[b * NGT + a]];  // sparse direct read
    float i2 = iouv * iouv;
    float m = sc * (i2 * i2 * i2);
    assigned[p] = a;
    aMetric[p] = m;
    atomicMax(&maxM[b * NGT + a], __float_as_uint(m));
    atomicMax(&maxI[b * NGT + a], __float_as_uint(iouv));
}

// ---------- finalize: all 5 outputs; strided regions via LDS transpose ----------
__global__ __launch_bounds__(256) void finalize_kernel(
        const float* __restrict__ gt,
        const int* __restrict__ labels,
        const int* __restrict__ crowd,
        const int* __restrict__ assigned,
        const float* __restrict__ aMetric,
        const unsigned* __restrict__ maxM,
        const unsigned* __restrict__ maxI,
        float* __restrict__ out) {
    __shared__ float lds[CC * 257];
    const int t = threadIdx.x;
    const int b = blockIdx.x / (LL / 256);
    const int j0 = (blockIdx.x % (LL / 256)) * 256;
    const int p = blockIdx.x * 256 + t;
    const size_t O0 = 0;
    const size_t O1 = (size_t)BB * LL;
    const size_t O2 = O1 + (size_t)BB * LL * 5;
    const size_t O3 = O2 + (size_t)BB * LL * CC;
    const size_t O4 = O3 + (size_t)BB * LL;

    int a = assigned[p];
    bool pos = (a >= 0);
    int idx = pos ? a : 0;
    int lab = labels[b * NGT + idx];
    int cw  = crowd[b * NGT + idx];
    out[O0 + p] = pos ? (float)lab : (float)BGI;
    out[O3 + p] = (float)idx;
    out[O4 + p] = (float)cw;
    float per = 0.0f;
    if (pos) {
        float mm = __uint_as_float(maxM[b * NGT + a]);
        float mi = __uint_as_float(maxI[b * NGT + a]);
        per = aMetric[p] / (mm + EPSF) * mi;
    }

    // assigned_scores (stride-15) via LDS transpose
    float keep = (pos && cw == 0) ? per : 0.0f;
#pragma unroll
    for (int c = 0; c < CC; ++c)
        lds[c * 257 + t] = (c == lab) ? keep : 0.0f;
    __syncthreads();
    float* o2 = out + O2 + (size_t)(b * LL + j0) * CC;
#pragma unroll
    for (int k = 0; k < CC; ++k) {
        int g = k * 256 + t;
        o2[g] = lds[(g % CC) * 257 + g / CC];
    }
    __syncthreads();

    // assigned_rboxes (stride-5) via LDS transpose
    const float* gb = gt + (size_t)(b * NGT + idx) * 5;
#pragma unroll
    for (int k = 0; k < 5; ++k)
        lds[k * 257 + t] = gb[k];
    __syncthreads();
    float* o1 = out + O1 + (size_t)(b * LL + j0) * 5;
#pragma unroll
    for (int k = 0; k < 5; ++k) {
        int g = k * 256 + t;
        o1[g] = lds[(g % 5) * 257 + g / 5];
    }
}

extern "C" void kernel_launch(void* const* d_in, const int* in_sizes, int n_in,
                              void* d_out, int out_size, void* d_ws, size_t ws_size,
                              hipStream_t stream) {
    const float* pred_scores = (const float*)d_in[0];
    const float* pred_rboxes = (const float*)d_in[1];
    const float* anchor_pts  = (const float*)d_in[2];
    const int*   gt_labels   = (const int*)d_in[3];
    const float* gt_bboxes   = (const float*)d_in[4];
    // d_in[5] = gt_poses (unused)
    const int*   gt_crowd    = (const int*)d_in[6];
    const float* pad_gt      = (const float*)d_in[7];
    float* out = (float*)d_out;

    char* ws = (char*)d_ws;
    size_t off = 0;
    auto alloc = [&](size_t bytes) {
        void* pp = ws + off;
        off += (bytes + 255) & ~(size_t)255;
        return pp;
    };
    float4* pbox  = (float4*)alloc((size_t)BB * LL * 16);
    float*  parea = (float*)alloc((size_t)BB * LL * 4);
    float4* gbox  = (float4*)alloc((size_t)BB * NGT * 16);
    float4* gtrig = (float4*)alloc((size_t)BB * NGT * 16);
    float4* ggeom = (float4*)alloc((size_t)BB * NGT * 16);
    int* cnt        = (int*)alloc((size_t)BB * LL * 4);
    int* claim      = (int*)alloc((size_t)BB * LL * 4);
    unsigned* maxM  = (unsigned*)alloc((size_t)BB * NGT * 4);
    unsigned* maxI  = (unsigned*)alloc((size_t)BB * NGT * 4);
    int*   assigned = (int*)alloc((size_t)BB * LL * 4);
    float* aMetric  = (float*)alloc((size_t)BB * LL * 4);
    u64*   candK    = (u64*)alloc((size_t)BB * NGT * SSEG * KTOP * 8);

    prep_kernel<<<dim3(BB * LL / 256), dim3(256), 0, stream>>>(
        pred_rboxes, gt_bboxes, pad_gt,
        pbox, parea, gbox, gtrig, ggeom, cnt, claim, maxM, maxI);
    topk_part1<<<dim3(SSEG / 4, BB * NGT), dim3(256), 0, stream>>>(
        pred_scores, gt_labels, anchor_pts, pbox, parea, gbox, gtrig, ggeom, candK);
    topk_part2<<<dim3(BB * NGT), dim3(256), 0, stream>>>(
        gtrig, ggeom, anchor_pts, candK, cnt, claim);
    resolve_kernel<<<dim3(LL / 256, BB), dim3(256), 0, stream>>>(
        pred_scores, gt_labels, pbox, parea, gbox, gtrig, cnt, claim,
        assigned, aMetric, maxM, maxI);
    finalize_kernel<<<dim3(BB * LL / 256), dim3(256), 0, stream>>>(
        gt_bboxes, gt_labels, gt_crowd, assigned, aMetric, maxM, maxI, out);
}